// Round 10
// baseline (210.205 us; speedup 1.0000x reference)
//
#include <hip/hip_runtime.h>
#include <hip/hip_bf16.h>
#include <math.h>

#define SEQ 2048
#define DM 1024
#define NH 16
#define HD 64
#define NBH 32      // B*NH
#define MTOT 4096   // B*SEQ

typedef __attribute__((ext_vector_type(8))) short short8;
typedef __attribute__((ext_vector_type(4))) float floatx4;
typedef __attribute__((ext_vector_type(8))) unsigned short u16x8;
typedef __attribute__((ext_vector_type(4))) unsigned short u16x4;

__device__ __forceinline__ unsigned short f2bf(float f) {
    unsigned int u = __float_as_uint(f);
    u += 0x7FFFu + ((u >> 16) & 1u);    // round-to-nearest-even
    return (unsigned short)(u >> 16);
}

#define AS1C const __attribute__((address_space(1))) void*
#define AS3  __attribute__((address_space(3))) void*

// 0.125 * log2(e): folds the 1/sqrt(64) score scale AND the exp->exp2
// conversion into Q's projection epilogue.
#define QSCALE 0.18033688011112042f

// ---------------------------------------------------------------------------
// x fp32 [4096][1024] -> bf16 same layout. 8 elems/thread.
// ---------------------------------------------------------------------------
__global__ __launch_bounds__(256) void cvt_x_kernel(
    const float* __restrict__ x, unsigned short* __restrict__ xb)
{
    size_t base = ((size_t)blockIdx.x * 256 + threadIdx.x) * 8;
    float4 a = *(const float4*)(x + base);
    float4 b = *(const float4*)(x + base + 4);
    u16x8 o;
    o[0]=f2bf(a.x); o[1]=f2bf(a.y); o[2]=f2bf(a.z); o[3]=f2bf(a.w);
    o[4]=f2bf(b.x); o[5]=f2bf(b.y); o[6]=f2bf(b.z); o[7]=f2bf(b.w);
    *(u16x8*)(xb + base) = o;
}

// ---------------------------------------------------------------------------
// W fp32 [K][N] -> Wt bf16 [N][K] (transpose+convert). grid (K/64, N/64, 4).
// ---------------------------------------------------------------------------
__global__ __launch_bounds__(256) void cvt_w_kernel(
    const float* __restrict__ Wq, const float* __restrict__ Wk,
    const float* __restrict__ Wv, const float* __restrict__ Wo,
    unsigned short* __restrict__ Wt)
{
    __shared__ float Ls[64][65];
    const int z = blockIdx.z;
    const float* src = (z==0) ? Wq : (z==1) ? Wk : (z==2) ? Wv : Wo;
    unsigned short* dst = Wt + (size_t)z * DM * DM;
    const int tid = threadIdx.x;
    const int k0 = blockIdx.x * 64, n0 = blockIdx.y * 64;

    int r = tid >> 2, cseg = (tid & 3) * 16;
    #pragma unroll
    for (int e = 0; e < 4; ++e) {
        float4 v = *(const float4*)(src + (size_t)(k0 + r) * DM + n0 + cseg + e*4);
        Ls[r][cseg+e*4+0] = v.x; Ls[r][cseg+e*4+1] = v.y;
        Ls[r][cseg+e*4+2] = v.z; Ls[r][cseg+e*4+3] = v.w;
    }
    __syncthreads();
    int n = tid >> 2, kseg = (tid & 3) * 16;
    #pragma unroll
    for (int half = 0; half < 2; ++half) {
        u16x8 o;
        #pragma unroll
        for (int e = 0; e < 8; ++e) o[e] = f2bf(Ls[kseg + half*8 + e][n]);
        *(u16x8*)(dst + (size_t)(n0 + n) * DM + k0 + kseg + half*8) = o;
    }
}

// ---------------------------------------------------------------------------
// bf16 MFMA GEMM core: C[128][128] per block, BK=64 as TWO proven BK=32
// chunks per barrier-pair (halves barrier count; short-K loops are
// barrier-drain heavy). LDS 32 KB, 3 blocks/CU.
// ---------------------------------------------------------------------------
#define GEMM_CORE(A_, Bt_, m0_, n0_)                                          \
    const int tid = threadIdx.x;                                              \
    const int wave = tid >> 6, lane = tid & 63;                               \
    const int quad = lane >> 4, l16 = lane & 15;                              \
    const int mh = (wave & 1) * 64, nh = (wave >> 1) * 64;                    \
    floatx4 acc[4][4];                                                        \
    _Pragma("unroll")                                                         \
    for (int i = 0; i < 4; ++i)                                               \
        _Pragma("unroll")                                                     \
        for (int j = 0; j < 4; ++j) acc[i][j] = (floatx4){0.f,0.f,0.f,0.f};   \
    {                                                                         \
        const int srow = wave*32 + (lane>>2);                                 \
        const int scol = (lane & 3) * 8;                                      \
        const unsigned short* ga = A_ + (size_t)(m0_ + srow)*DM + scol;       \
        const unsigned short* gb = Bt_ + (size_t)(n0_ + srow)*DM + scol;      \
        char* lA = (char*)As; char* lB = (char*)Bs;                           \
        for (int k0 = 0; k0 < DM; k0 += 64) {                                 \
            __syncthreads();                                                  \
            _Pragma("unroll")                                                 \
            for (int ch = 0; ch < 2; ++ch)                                    \
                _Pragma("unroll")                                             \
                for (int u = 0; u < 2; ++u) {                                 \
                    __builtin_amdgcn_global_load_lds(                         \
                        (AS1C)(ga + (size_t)u*16*DM + k0 + ch*32),            \
                        (AS3)(lA + ch*8192 + (wave*32 + u*16)*64), 16, 0, 0); \
                    __builtin_amdgcn_global_load_lds(                         \
                        (AS1C)(gb + (size_t)u*16*DM + k0 + ch*32),            \
                        (AS3)(lB + ch*8192 + (wave*32 + u*16)*64), 16, 0, 0); \
                }                                                             \
            __syncthreads();                                                  \
            _Pragma("unroll")                                                 \
            for (int ch = 0; ch < 2; ++ch) {                                  \
                short8 af[4], bf[4];                                          \
                _Pragma("unroll")                                             \
                for (int t = 0; t < 4; ++t) {                                 \
                    af[t] = *(const short8*)&As[ch][(mh + t*16 + l16)*32 + quad*8]; \
                    bf[t] = *(const short8*)&Bs[ch][(nh + t*16 + l16)*32 + quad*8]; \
                }                                                             \
                _Pragma("unroll")                                             \
                for (int mt = 0; mt < 4; ++mt)                                \
                    _Pragma("unroll")                                         \
                    for (int nt = 0; nt < 4; ++nt)                            \
                        acc[mt][nt] = __builtin_amdgcn_mfma_f32_16x16x32_bf16(\
                            af[mt], bf[nt], acc[mt][nt], 0, 0, 0);            \
            }                                                                 \
        }                                                                     \
    }

// ---------------------------------------------------------------------------
// QKV projection GEMM. grid (32, 8, 3): z=0 q(rope+QSCALE), 1 k(rope),
// 2 v -> V TRANSPOSED to global vtg[((b*NH+h)*64+dh)*SEQ + skey] where the
// key axis is SLOT-PERMUTED within each 32-key block: key 16t+4q+r sits at
// slot 8q+4t+r (matches attention's in-register S^T lane order).
// Q/K stored in PI-PERMUTED dh layout: pos 4*l16+p holds col p*16+l16;
// applied to both Q and K -> QK^T invariant.
// ---------------------------------------------------------------------------
__global__ __launch_bounds__(256, 3) void qkv_gemm_kernel(
    const unsigned short* __restrict__ xb, const unsigned short* __restrict__ Wt,
    const float* __restrict__ bq, const float* __restrict__ bk,
    const float* __restrict__ bv,
    unsigned short* __restrict__ qb, unsigned short* __restrict__ kb,
    unsigned short* __restrict__ vtg)
{
    __shared__ unsigned short As[2][128*32];
    __shared__ unsigned short Bs[2][128*32];
    const int z = blockIdx.z;
    const unsigned short* Bt = Wt + (size_t)z * DM * DM;
    const float* bias = (z==0) ? bq : (z==1) ? bk : bv;
    const int m0 = blockIdx.x * 128, n0 = blockIdx.y * 128;

    GEMM_CORE(xb, Bt, m0, n0)

    float bb[4];
    #pragma unroll
    for (int nt = 0; nt < 4; ++nt) bb[nt] = bias[n0 + nh + nt*16 + l16];

    if (z == 2) {
        // V^T epilogue with slot permutation: 4 rounds of LDS transpose.
        unsigned short* Tw = (wave & 1) ? (unsigned short*)Bs : (unsigned short*)As;
        const int b = m0 >> 11;
        const int bufsel = tid >> 7, nl = tid & 127;
        const int ng = n0 + nl, hh = ng >> 6, dhh = ng & 63;
        unsigned short* vrow = vtg + ((size_t)((b*NH + hh)*HD + dhh))*SEQ;
        #pragma unroll
        for (int t = 0; t < 4; ++t) {
            __syncthreads();
            #pragma unroll
            for (int nt = 0; nt < 4; ++nt)
                #pragma unroll
                for (int r = 0; r < 4; ++r)
                    Tw[(nh + nt*16 + l16)*24 + quad*4 + r] =
                        f2bf(acc[t][nt][r] + bb[nt]);
            __syncthreads();
            const unsigned short* T2 = bufsel ? (const unsigned short*)Bs
                                              : (const unsigned short*)As;
            int sbase = (m0 & 2047) + bufsel*64 + t*16;   // 16-aligned
            int t32 = (sbase >> 4) & 1;
            int sb32 = sbase & ~31;
            #pragma unroll
            for (int gq = 0; gq < 4; ++gq) {
                u16x4 v4 = *(const u16x4*)&T2[nl*24 + gq*4];
                *(u16x4*)(vrow + sb32 + gq*8 + t32*4) = v4;
            }
        }
    } else {
        unsigned short* outh = (z==0) ? qb : kb;
        const float scl = (z == 0) ? QSCALE : 1.0f;
        const int h = (n0 + nh) >> 6;   // one head per n-half
        float inv0 = __expf(-(float)l16        * 0.28782313662425572f);
        float inv1 = __expf(-(float)(l16 + 16) * 0.28782313662425572f);
        #pragma unroll
        for (int mt = 0; mt < 4; ++mt)
            #pragma unroll
            for (int r = 0; r < 4; ++r) {
                int m = m0 + mh + mt*16 + quad*4 + r;
                int b = m >> 11, s = m & (SEQ-1);
                float s0, c0, s1, c1;
                __sincosf((float)s * inv0, &s0, &c0);
                __sincosf((float)s * inv1, &s1, &c1);
                float a0 = acc[mt][0][r] + bb[0];   // col l16
                float a1 = acc[mt][1][r] + bb[1];   // col l16+16
                float a2 = acc[mt][2][r] + bb[2];   // col l16+32
                float a3 = acc[mt][3][r] + bb[3];   // col l16+48
                u16x4 o;
                o[0] = f2bf((a0*c0 - a2*s0) * scl);
                o[1] = f2bf((a1*c1 - a3*s1) * scl);
                o[2] = f2bf((a2*c0 + a0*s0) * scl);
                o[3] = f2bf((a3*c1 + a1*s1) * scl);
                *(u16x4*)(outh + ((size_t)((b*NH + h)*SEQ + s))*HD + 4*l16) = o;
            }
    }
}

// ---------------------------------------------------------------------------
// Output GEMM: out[M][DM] fp32 = ctx_bf16 @ Wto^T + bo. grid (32, 8).
// ---------------------------------------------------------------------------
__global__ __launch_bounds__(256, 3) void out_gemm_kernel(
    const unsigned short* __restrict__ ctxb, const unsigned short* __restrict__ Wto,
    const float* __restrict__ bo, float* __restrict__ outf)
{
    __shared__ unsigned short As[2][128*32];
    __shared__ unsigned short Bs[2][128*32];
    const int m0 = blockIdx.x * 128, n0 = blockIdx.y * 128;

    GEMM_CORE(ctxb, Wto, m0, n0)

    float bb[4];
    #pragma unroll
    for (int nt = 0; nt < 4; ++nt) bb[nt] = bo[n0 + nh + nt*16 + l16];
    #pragma unroll
    for (int mt = 0; mt < 4; ++mt)
        #pragma unroll
        for (int r = 0; r < 4; ++r) {
            int m = m0 + mh + mt*16 + quad*4 + r;
            #pragma unroll
            for (int nt = 0; nt < 4; ++nt) {
                int n = n0 + nh + nt*16 + l16;
                outf[(size_t)m*DM + n] = acc[mt][nt][r] + bb[nt];
            }
        }
}

// ---------------------------------------------------------------------------
// Flash attention v4: S^T=K·Q^T keeps P in registers (round 9) + LDS
// DOUBLE-BUFFERED K/V staging: the DMA for iter k+1 is issued right after
// the barrier that opens iter k, into the other 32 KB buffer. Each wave's
// own vmcnt drain at the NEXT barrier then covers a DMA that had the whole
// compute phase to finish -> per-iter exposed drain collapses to the join.
// (m99-style dbuf was neutral for GEMM at 12 waves/CU; here occupancy is
// only 8 waves/CU so the drain was exposed.) LDS 64.1 KB, 2 blocks/CU.
// Everything else identical to round 9 (XOR swizzle on (row>>2)&3,
// slot-permuted V^T, no-max exp2 softmax, XCD-local bh).
// ---------------------------------------------------------------------------
__global__ __launch_bounds__(256, 2) void attn_mfma_kernel(
    const unsigned short* __restrict__ Q, const unsigned short* __restrict__ K,
    const unsigned short* __restrict__ Vtg, unsigned short* __restrict__ ctxb)
{
    __shared__ unsigned short KVs[2][16384];  // [buf][ Ks 8192 | Vt 8192 ]
    __shared__ float Lred[4][32];

    const int tid  = threadIdx.x;
    const int wave = tid >> 6, lane = tid & 63;
    const int quad = lane >> 4, l16 = lane & 15;
    const int bh = blockIdx.x & 31;           // XCD-local (bh -> XCD bh&7)
    const int qt = blockIdx.x >> 5;

    const unsigned short* Qb = Q + (size_t)bh * SEQ * HD;
    const unsigned short* Kb = K + (size_t)bh * SEQ * HD;
    const unsigned short* Vb = Vtg + (size_t)bh * HD * SEQ;

    // Q fragments in registers: qf[qg][s] = Q[q = wave*32+qg*16+l16][d s-half]
    short8 qf[2][2];
    #pragma unroll
    for (int qg = 0; qg < 2; ++qg) {
        const unsigned short* qrow =
            Qb + (size_t)(qt*128 + wave*32 + qg*16 + l16)*HD;
        qf[qg][0] = *(const short8*)(qrow + quad*8);
        qf[qg][1] = *(const short8*)(qrow + 32 + quad*8);
    }

    // DMA staging: waves 0-1 stage K (16KB), waves 2-3 stage V (16KB);
    // 8 issues x 16B/thread. Granule XOR on (row>>2)&3.
    const unsigned short* gsrc[8];
    int loff[8];                              // byte offset within a buffer
    int step;
    if (wave < 2) {
        #pragma unroll
        for (int u = 0; u < 8; ++u) {
            int G = u*128 + wave*64 + lane;      // granule 0..1023
            int gl = G & 3, key = (G >> 2) & 127, s = G >> 9;
            gsrc[u] = Kb + (size_t)key*HD + s*32 + (gl ^ ((key>>2)&3))*8;
            loff[u] = G*16;
        }
        step = 128*HD;
    } else {
        #pragma unroll
        for (int u = 0; u < 8; ++u) {
            int G = u*128 + (wave-2)*64 + lane;
            int gl = G & 3, d = (G >> 2) & 63, g = G >> 8;
            gsrc[u] = Vb + (size_t)d*SEQ + g*32 + (gl ^ ((d>>2)&3))*8;
            loff[u] = 16384 + G*16;
        }
        step = 128;
    }
    char* lbase = (char*)KVs;

    float l_p[2] = {0.f, 0.f};
    floatx4 Oacc[2][4];
    #pragma unroll
    for (int qg = 0; qg < 2; ++qg)
        #pragma unroll
        for (int dt = 0; dt < 4; ++dt) Oacc[qg][dt] = (floatx4){0.f,0.f,0.f,0.f};

    const int swz = (quad ^ (l16 >> 2)) * 8;

    // prologue: stage tile 0 into buffer 0
    #pragma unroll
    for (int u = 0; u < 8; ++u)
        __builtin_amdgcn_global_load_lds((AS1C)gsrc[u], (AS3)(lbase + loff[u]), 16, 0, 0);
    #pragma unroll
    for (int u = 0; u < 8; ++u) gsrc[u] += step;

    for (int kt = 0; kt < SEQ/128; ++kt) {
        __syncthreads();   // own-DMA drained (had full prev compute) + join
        if (kt + 1 < SEQ/128) {
            char* nb = lbase + ((kt + 1) & 1) * 32768;
            #pragma unroll
            for (int u = 0; u < 8; ++u)
                __builtin_amdgcn_global_load_lds((AS1C)gsrc[u], (AS3)(nb + loff[u]), 16, 0, 0);
            #pragma unroll
            for (int u = 0; u < 8; ++u) gsrc[u] += step;
        }
        const unsigned short* Kbuf = KVs[kt & 1];
        const unsigned short* Vbuf = KVs[kt & 1] + 8192;

        #pragma unroll
        for (int g = 0; g < 4; ++g) {            // 32-key groups
            // S^T = K @ Q^T for the group's two 16-key tiles
            floatx4 Sc[2][2];                    // [t][qg]
            #pragma unroll
            for (int t = 0; t < 2; ++t)
                #pragma unroll
                for (int qg = 0; qg < 2; ++qg) Sc[t][qg] = (floatx4){0.f,0.f,0.f,0.f};
            #pragma unroll
            for (int t = 0; t < 2; ++t) {
                const int c = g*2 + t;
                #pragma unroll
                for (int s = 0; s < 2; ++s) {
                    short8 af = *(const short8*)&Kbuf[s*4096 + (c*16 + l16)*32 + swz];
                    #pragma unroll
                    for (int qg = 0; qg < 2; ++qg)
                        Sc[t][qg] = __builtin_amdgcn_mfma_f32_16x16x32_bf16(
                            af, qf[qg][s], Sc[t][qg], 0, 0, 0);
                }
            }
            // exp2 + pack into PV A-frags (registers only)
            short8 a8[2];
            #pragma unroll
            for (int qg = 0; qg < 2; ++qg) {
                float p[8];
                #pragma unroll
                for (int t = 0; t < 2; ++t)
                    #pragma unroll
                    for (int r = 0; r < 4; ++r) p[t*4+r] = exp2f(Sc[t][qg][r]);
                l_p[qg] += ((p[0]+p[1]) + (p[2]+p[3])) + ((p[4]+p[5]) + (p[6]+p[7]));
                u16x8 av;
                #pragma unroll
                for (int e = 0; e < 4; ++e) {
                    __hip_bfloat162 w = __float22bfloat162_rn(make_float2(p[2*e], p[2*e+1]));
                    unsigned int uu; __builtin_memcpy(&uu, &w, 4);
                    av[2*e]   = (unsigned short)(uu & 0xFFFF);
                    av[2*e+1] = (unsigned short)(uu >> 16);
                }
                __builtin_memcpy(&a8[qg], &av, 16);
            }
            // O += P @ V (slot-permuted key order on both sides)
            #pragma unroll
            for (int dt = 0; dt < 4; ++dt) {
                short8 bf = *(const short8*)&Vbuf[g*2048 + (dt*16 + l16)*32 + swz];
                #pragma unroll
                for (int qg = 0; qg < 2; ++qg)
                    Oacc[qg][dt] = __builtin_amdgcn_mfma_f32_16x16x32_bf16(
                        a8[qg], bf, Oacc[qg][dt], 0, 0, 0);
            }
        }
    }

    // l: reduce across quads (lane bits 4,5), then transpose via tiny LDS
    #pragma unroll
    for (int qg = 0; qg < 2; ++qg) {
        l_p[qg] += __shfl_xor(l_p[qg], 16);
        l_p[qg] += __shfl_xor(l_p[qg], 32);
        Lred[wave][qg*16 + l16] = l_p[qg];   // same value across quads
    }

    int b = bh >> 4, h = bh & 15;
    #pragma unroll
    for (int qg = 0; qg < 2; ++qg)
        #pragma unroll
        for (int r = 0; r < 4; ++r) {
            int sr = qt*128 + wave*32 + qg*16 + quad*4 + r;
            float invl = 1.0f / Lred[wave][qg*16 + quad*4 + r];
            unsigned short* dst = ctxb + ((size_t)(b*SEQ + sr))*DM + h*HD;
            #pragma unroll
            for (int dt = 0; dt < 4; ++dt)
                dst[dt*16 + l16] = f2bf(Oacc[qg][dt][r] * invl);
        }
}

// ---------------------------------------------------------------------------
extern "C" void kernel_launch(void* const* d_in, const int* in_sizes, int n_in,
                              void* d_out, int out_size, void* d_ws, size_t ws_size,
                              hipStream_t stream) {
    const float* x  = (const float*)d_in[0];
    const float* Wq = (const float*)d_in[1];
    const float* bq = (const float*)d_in[2];
    const float* Wk = (const float*)d_in[3];
    const float* bk = (const float*)d_in[4];
    const float* Wv = (const float*)d_in[5];
    const float* bv = (const float*)d_in[6];
    const float* Wo = (const float*)d_in[7];
    const float* bo = (const float*)d_in[8];
    float* out = (float*)d_out;

    char* ws = (char*)d_ws;
    unsigned short* xb   = (unsigned short*)(ws);                    // 8 MB
    unsigned short* Wt   = (unsigned short*)(ws +  8u*1024*1024);    // 8 MB (4x2)
    unsigned short* qb   = (unsigned short*)(ws + 16u*1024*1024);    // 8 MB
    unsigned short* kb   = (unsigned short*)(ws + 24u*1024*1024);    // 8 MB
    unsigned short* vtg  = (unsigned short*)(ws + 32u*1024*1024);    // 8 MB (V^T)
    unsigned short* ctxb = (unsigned short*)(ws + 40u*1024*1024);    // 8 MB

    cvt_x_kernel<<<(MTOT*DM/8)/256, 256, 0, stream>>>(x, xb);
    cvt_w_kernel<<<dim3(DM/64, DM/64, 4), 256, 0, stream>>>(Wq, Wk, Wv, Wo, Wt);

    qkv_gemm_kernel<<<dim3(MTOT/128, DM/128, 3), 256, 0, stream>>>(
        xb, Wt, bq, bk, bv, qb, kb, vtg);

    attn_mfma_kernel<<<512, 256, 0, stream>>>(qb, kb, vtg, ctxb);

    out_gemm_kernel<<<dim3(MTOT/128, DM/128), 256, 0, stream>>>(
        ctxb, Wt + (size_t)3*DM*DM, bo, out);
    (void)in_sizes; (void)n_in; (void)out_size; (void)ws_size;
}